// Round 14
// baseline (223.608 us; speedup 1.0000x reference)
//
#include <hip/hip_runtime.h>
#include <math.h>

#define L 4096
#define D 1024
#define H 16
#define KV 4
#define DH 64
// G = H/KV = 4

typedef __attribute__((ext_vector_type(8))) short bf16x8;
typedef __attribute__((ext_vector_type(4))) float f32x4;
typedef __attribute__((ext_vector_type(16))) float f32x16;
typedef __attribute__((ext_vector_type(2))) unsigned int u32x2;

static __device__ __forceinline__ unsigned short f2bf(float f) {
    unsigned u = __float_as_uint(f);
    u = (u + 0x7FFF + ((u >> 16) & 1)) >> 16;   // RNE
    return (unsigned short)u;
}

static __device__ __forceinline__ float bf2f(unsigned short s) {
    return __uint_as_float((unsigned)s << 16);
}

static __device__ __forceinline__ bf16x8 mk8(unsigned a, unsigned b, unsigned c, unsigned d) {
    union { unsigned u[4]; bf16x8 v; } x;
    x.u[0] = a; x.u[1] = b; x.u[2] = c; x.u[3] = d;
    return x.v;
}

#define EXP2F(x) __builtin_amdgcn_exp2f(x)
#define ZERO16 ((f32x16){0.f,0.f,0.f,0.f,0.f,0.f,0.f,0.f,0.f,0.f,0.f,0.f,0.f,0.f,0.f,0.f})

// async global->LDS, 16B per lane; dst must be wave-uniform base (HW: base + lane*16)
#define GLD16(src, dst) \
    __builtin_amdgcn_global_load_lds((__attribute__((address_space(1))) void*)(src), \
                                     (__attribute__((address_space(3))) void*)(dst), 16, 0, 0)

// ---------------------------------------------------------------------------
// prep: x fp32->bf16, and the four weight transposes (dst[n][k] bf16, K=1024).
// ---------------------------------------------------------------------------
__global__ __launch_bounds__(256) void prep_kernel(
        const float* __restrict__ x,  const float* __restrict__ Wq,
        const float* __restrict__ Wk, const float* __restrict__ Wv,
        const float* __restrict__ Wo,
        unsigned short* __restrict__ xb, unsigned short* __restrict__ WqkvT,
        unsigned short* __restrict__ WoT) {
    const int b = blockIdx.x, tid = threadIdx.x;
    if (b < 4096) {
        int i = (b * 256 + tid) * 4;
        float4 v = *(const float4*)&x[i];
        ushort4 o;
        o.x = f2bf(v.x); o.y = f2bf(v.y); o.z = f2bf(v.z); o.w = f2bf(v.w);
        *(ushort4*)&xb[i] = o;
        return;
    }
    __shared__ float t[32][33];
    const float* src; unsigned short* dst; int N, n0, k0;
    if (b < 5120)      { int tq = b - 4096; src = Wq; dst = WqkvT;                     N = 1024; n0 = (tq & 31) * 32; k0 = (tq >> 5) * 32; }
    else if (b < 5376) { int tq = b - 5120; src = Wk; dst = WqkvT + (size_t)1024*1024; N = 256;  n0 = (tq & 7)  * 32; k0 = (tq >> 3) * 32; }
    else if (b < 5632) { int tq = b - 5376; src = Wv; dst = WqkvT + (size_t)1280*1024; N = 256;  n0 = (tq & 7)  * 32; k0 = (tq >> 3) * 32; }
    else               { int tq = b - 5632; src = Wo; dst = WoT;                       N = 1024; n0 = (tq & 31) * 32; k0 = (tq >> 5) * 32; }
    const int tx = tid & 31, ty = tid >> 5;
    #pragma unroll
    for (int j = 0; j < 4; ++j)
        t[ty + 8 * j][tx] = src[(size_t)(k0 + ty + 8 * j) * N + n0 + tx];
    __syncthreads();
    #pragma unroll
    for (int j = 0; j < 4; ++j)
        dst[(size_t)(n0 + ty + 8 * j) * 1024 + k0 + tx] = f2bf(t[tx][ty + 8 * j]);
}

// ---------------------------------------------------------------------------
// bf16 MFMA GEMM (fp32 out) for the Wo projection. Tile 64x128, 512 blocks.
// ---------------------------------------------------------------------------
__global__ __launch_bounds__(256) void gemm_bf16(const unsigned short* __restrict__ A,
                                                 const unsigned short* __restrict__ BT,
                                                 float* __restrict__ C,
                                                 int M, int N, int K) {
    __shared__ unsigned short As[64 * 32];
    __shared__ unsigned short Bs[128 * 32];

    const int tid  = threadIdx.x;
    const int w    = tid >> 6;
    const int lane = tid & 63;
    const int c    = lane & 15;
    const int quad = lane >> 4;
    const int wy = w >> 1, wx = w & 1;
    const int row0 = blockIdx.y * 64;
    const int col0 = blockIdx.x * 128;

    const int ld_row = lane >> 2;
    const int ld_col = (lane & 3) * 8;

    f32x4 acc[2][4];
    #pragma unroll
    for (int mt = 0; mt < 2; ++mt)
        #pragma unroll
        for (int nt = 0; nt < 4; ++nt)
            acc[mt][nt] = (f32x4){0.f, 0.f, 0.f, 0.f};

    for (int k0 = 0; k0 < K; k0 += 32) {
        __syncthreads();
        GLD16(&A [(size_t)(row0 + w * 16 + ld_row)      * K + k0 + ld_col], &As[w * 512]);
        GLD16(&BT[(size_t)(col0 + w * 16 + ld_row)      * K + k0 + ld_col], &Bs[w * 512]);
        GLD16(&BT[(size_t)(col0 + w * 16 + 64 + ld_row) * K + k0 + ld_col], &Bs[w * 512 + 2048]);
        __syncthreads();

        bf16x8 af[2], bfr[4];
        #pragma unroll
        for (int mt = 0; mt < 2; ++mt)
            af[mt] = *(const bf16x8*)&As[(wy * 32 + mt * 16 + c) * 32 + quad * 8];
        #pragma unroll
        for (int nt = 0; nt < 4; ++nt)
            bfr[nt] = *(const bf16x8*)&Bs[(wx * 64 + nt * 16 + c) * 32 + quad * 8];

        #pragma unroll
        for (int mt = 0; mt < 2; ++mt)
            #pragma unroll
            for (int nt = 0; nt < 4; ++nt)
                acc[mt][nt] = __builtin_amdgcn_mfma_f32_16x16x32_bf16(af[mt], bfr[nt], acc[mt][nt], 0, 0, 0);
    }

    #pragma unroll
    for (int mt = 0; mt < 2; ++mt)
        #pragma unroll
        for (int nt = 0; nt < 4; ++nt)
            #pragma unroll
            for (int r = 0; r < 4; ++r)
                C[(size_t)(row0 + wy * 32 + mt * 16 + quad * 4 + r) * N
                  + col0 + wx * 64 + nt * 16 + c] = acc[mt][nt][r];
}

// ---------------------------------------------------------------------------
// Fused QKV GEMM + RoPE epilogue. Tile 64x128, grid (12,64) = 768 blocks.
// K per-head contiguous (kb[kv][l][DH]); V transposed (vbT[kv*DH+d][l]).
// ---------------------------------------------------------------------------
__global__ __launch_bounds__(256) void gemm_qkv_rope(
        const unsigned short* __restrict__ A,
        const unsigned short* __restrict__ BT,
        unsigned short* __restrict__ qb,
        unsigned short* __restrict__ kbuf,
        unsigned short* __restrict__ vbT) {
    __shared__ unsigned short As[64 * 32];
    __shared__ unsigned short Bs[128 * 32];

    const int tid  = threadIdx.x;
    const int w    = tid >> 6;
    const int lane = tid & 63;
    const int c    = lane & 15;
    const int quad = lane >> 4;
    const int wy = w >> 1, wx = w & 1;
    const int row0 = blockIdx.y * 64;
    const int col0 = blockIdx.x * 128;

    const int ld_row = lane >> 2;
    const int ld_col = (lane & 3) * 8;

    f32x4 acc[2][4];
    #pragma unroll
    for (int mt = 0; mt < 2; ++mt)
        #pragma unroll
        for (int nt = 0; nt < 4; ++nt)
            acc[mt][nt] = (f32x4){0.f, 0.f, 0.f, 0.f};

    for (int k0 = 0; k0 < 1024; k0 += 32) {
        __syncthreads();
        GLD16(&A [(size_t)(row0 + w * 16 + ld_row)      * 1024 + k0 + ld_col], &As[w * 512]);
        GLD16(&BT[(size_t)(col0 + w * 16 + ld_row)      * 1024 + k0 + ld_col], &Bs[w * 512]);
        GLD16(&BT[(size_t)(col0 + w * 16 + 64 + ld_row) * 1024 + k0 + ld_col], &Bs[w * 512 + 2048]);
        __syncthreads();

        bf16x8 af[2], bfr[4];
        #pragma unroll
        for (int mt = 0; mt < 2; ++mt)
            af[mt] = *(const bf16x8*)&As[(wy * 32 + mt * 16 + c) * 32 + quad * 8];
        #pragma unroll
        for (int nt = 0; nt < 4; ++nt)
            bfr[nt] = *(const bf16x8*)&Bs[(wx * 64 + nt * 16 + c) * 32 + quad * 8];

        #pragma unroll
        for (int mt = 0; mt < 2; ++mt)
            #pragma unroll
            for (int nt = 0; nt < 4; ++nt)
                acc[mt][nt] = __builtin_amdgcn_mfma_f32_16x16x32_bf16(af[mt], bfr[nt], acc[mt][nt], 0, 0, 0);
    }

    const int colb = col0 + wx * 64;
    if (colb < 1280) {
        unsigned short* dst; size_t ls, hs; int hh; float scale;
        if (colb < 1024) { dst = qb;   ls = H * DH; hs = DH;            hh = colb >> 6;          scale = 0.18033688011112042f; }
        else             { dst = kbuf; ls = DH;     hs = (size_t)L * DH; hh = (colb - 1024) >> 6; scale = 1.0f; }
        #pragma unroll
        for (int nt = 0; nt < 2; ++nt) {
            int d = nt * 16 + c;
            float invf = EXP2F((float)d * -0.4152410118609203f);
            #pragma unroll
            for (int mt = 0; mt < 2; ++mt)
                #pragma unroll
                for (int r = 0; r < 4; ++r) {
                    int l = row0 + wy * 32 + mt * 16 + quad * 4 + r;
                    float ang = (float)l * invf;
                    float sn = __sinf(ang), cs = __cosf(ang);
                    float x1 = acc[mt][nt][r], x2 = acc[mt][nt + 2][r];
                    dst[(size_t)l * ls + (size_t)hh * hs + d]      = f2bf((x1 * cs - x2 * sn) * scale);
                    dst[(size_t)l * ls + (size_t)hh * hs + d + 32] = f2bf((x2 * cs + x1 * sn) * scale);
                }
        }
    } else {
        // V^T: vbT[(vh*DH + d) * L + l], packed 4 contiguous l per store
        int vh = (colb - 1280) >> 6;
        #pragma unroll
        for (int nt = 0; nt < 4; ++nt)
            #pragma unroll
            for (int mt = 0; mt < 2; ++mt) {
                int l = row0 + wy * 32 + mt * 16 + quad * 4;
                ushort4 o;
                o.x = f2bf(acc[mt][nt][0]); o.y = f2bf(acc[mt][nt][1]);
                o.z = f2bf(acc[mt][nt][2]); o.w = f2bf(acc[mt][nt][3]);
                *(ushort4*)&vbT[(size_t)(vh * DH + nt * 16 + c) * L + l] = o;
            }
    }
}

// ---------------------------------------------------------------------------
// MFMA attention, 32x32x16 — FLASH-DECODING GRID SPLIT. Grid (64, KV, 2) =
// 512 blocks = 2 blocks/CU = 16 waves/CU = 4 waves/SIMD. Per-wave body is
// byte-identical to R13's (~108 VGPR, 512-thr block — the only shape the
// compiler compiles well, per R5-R10). Block kh handles keys
// [kh*2048, kh*2048+2048) (g splits it 2x internally, 16 iters of 64).
//
// R13 post-mortem: every structural variant (barrier/no-barrier, scattered/
// coalesced staging) lands at 95-106 us because each iteration's dependent
// chain (St MFMAs -> exp2 -> pack -> PV MFMAs) is ~7300 cyc while pipe work
// is ~1500 -> latency-bound at 2 waves/SIMD. 4 full-fat waves/SIMD halves
// the exposed latency. Softmax partials are ADDITIVE (no max-rescale), so
// each block writes unnormalized bf16 O-partials + fp32 rowsums; the tiny
// attn_combine kernel merges the two key-halves and normalizes.
// LDS 66 KB/block (x2 = 132 <= 160 OK). All outputs overlay dead buffers.
// NOTE (R2): plain loop body only — no [&] lambda. NOTE (R10): 1024-thr
// blocks force a 64-VGPR binary; stay at 512 thr.
// ---------------------------------------------------------------------------
__global__ __attribute__((amdgpu_flat_work_group_size(512, 512), amdgpu_waves_per_eu(2)))
void attn_mfma_kernel(
        const unsigned short* __restrict__ qb,
        const unsigned short* __restrict__ kb,    // [kv][l][DH]
        const unsigned short* __restrict__ vbT,   // [kv*DH + d][l]
        unsigned short* __restrict__ Op0,         // bf16 partial O, key-half 0
        unsigned short* __restrict__ Op1,         // bf16 partial O, key-half 1
        float* __restrict__ Rp) {                 // fp32 rowsums [kh][l][H]
    __shared__ __align__(16) unsigned short Tiles[2][2][2][64][64];  // 64 KB [K/V][grp][buf][row][64]
    __shared__ __align__(16) float Rs[8][2][32];                     //  2 KB rowsums [wave][qt][q]

    const int tid  = threadIdx.x;
    const int w    = tid >> 6;        // 0..7
    const int lane = tid & 63;
    const int c32  = lane & 31;
    const int hi   = lane >> 5;
    const int g    = w >> 2;          // key group within block
    const int kv = blockIdx.y;
    const int kh = blockIdx.z;        // key half (grid split)
    const int h  = kv * 4 + (w & 3);
    const int q0 = blockIdx.x * 64;
    const int s_base = kh * 2048 + g * 1024;

    // ---- staging geometry (R13): slab s covers rows s*8..s*8+7; lane l
    // loads row lr8=l>>3, source 16B-chunk (l&7)^lr8 -> phys chunk l&7.
    const int sw  = w & 3;
    const int lr8 = lane >> 3, lc8 = lane & 7;
    const unsigned short* kstage = kb  + ((size_t)kv * L + s_base + lr8) * DH + ((lc8 ^ lr8) << 3);
    const unsigned short* vstage = vbT + ((size_t)kv * DH + lr8) * L + s_base + ((lc8 ^ lr8) << 3);
    unsigned short* KtB = &Tiles[0][g][0][0][0];
    unsigned short* VtB = &Tiles[1][g][0][0][0];

    // Q B-frags: col=q=c32, k-elems d = kd*16 + hi*8 + j
    bf16x8 qf[2][4];
    {
        const unsigned short* qbase = qb + ((size_t)(q0 + c32) * H + h) * DH + hi * 8;
        #pragma unroll
        for (int qt = 0; qt < 2; ++qt)
            #pragma unroll
            for (int kd = 0; kd < 4; ++kd)
                qf[qt][kd] = *(const bf16x8*)&qbase[qt * 32 * H * DH + kd * 16];
    }

    f32x16 oacc[2][2];    // [qt][dt]: col=d=dt*32+c32, row=q=(r&3)+8(r>>2)+4hi
    #pragma unroll
    for (int qt = 0; qt < 2; ++qt)
        #pragma unroll
        for (int dt = 0; dt < 2; ++dt)
            oacc[qt][dt] = ZERO16;
    float rsum[2] = {0.f, 0.f};   // per-lane partial rowsum, q = qt*32 + c32

    // ---- prologue: stage tile 0 into buf 0 (4 coalesced GLD16 per wave) ----
    GLD16(kstage + (size_t)(2 * sw)     * 8 * DH, KtB + (2 * sw)     * 512);
    GLD16(kstage + (size_t)(2 * sw + 1) * 8 * DH, KtB + (2 * sw + 1) * 512);
    GLD16(vstage + (size_t)(2 * sw)     * 8 * L,  VtB + (2 * sw)     * 512);
    GLD16(vstage + (size_t)(2 * sw + 1) * 8 * L,  VtB + (2 * sw + 1) * 512);

    for (int it = 0; it < 16; ++it) {
        const int bufo = (it & 1) * 4096;    // elems; [buf] stride in Tiles
        __syncthreads();   // drains own GLD16s -> buf staged; buf^1 reads done

        if (it != 15) {    // stage next tile into buf^1 (async, overlaps compute)
            const int nb = bufo ^ 4096;
            const size_t ko = (size_t)(it + 1) * 64 * DH;
            const int    vo = (it + 1) * 64;
            GLD16(kstage + ko + (size_t)(2 * sw)     * 8 * DH, KtB + nb + (2 * sw)     * 512);
            GLD16(kstage + ko + (size_t)(2 * sw + 1) * 8 * DH, KtB + nb + (2 * sw + 1) * 512);
            GLD16(vstage + vo + (size_t)(2 * sw)     * 8 * L,  VtB + nb + (2 * sw)     * 512);
            GLD16(vstage + vo + (size_t)(2 * sw + 1) * 8 * L,  VtB + nb + (2 * sw + 1) * 512);
        }

        #pragma unroll
        for (int kt2 = 0; kt2 < 2; ++kt2) {
            // K A-frags from LDS: key=kt2*32+c32, granule 2kd+hi (^ key&7)
            bf16x8 kfr[4];
            #pragma unroll
            for (int kd = 0; kd < 4; ++kd)
                kfr[kd] = *(const bf16x8*)&KtB[bufo + (kt2 * 32 + c32) * 64
                                + (((2 * kd + hi) ^ (c32 & 7)) << 3)];

            bf16x8 pf[2][2];   // [qt][f]: PV A-frags, keys kt2*32 + f*16 + hi*8 + j
            #pragma unroll
            for (int qt = 0; qt < 2; ++qt) {
                // St = K @ Q^T (32x32, K-dim = DH via 4 chained MFMAs)
                f32x16 s = ZERO16;
                #pragma unroll
                for (int kd = 0; kd < 4; ++kd)
                    s = __builtin_amdgcn_mfma_f32_32x32x16_bf16(kfr[kd], qf[qt][kd], s, 0, 0, 0);
                // exp2, truncate to bf16 domain (matches packed PV operand)
                float p[16];
                #pragma unroll
                for (int r = 0; r < 16; ++r)
                    p[r] = __uint_as_float(__float_as_uint(EXP2F(s[r])) & 0xFFFF0000u);
                // rowsum for q = qt*32+c32 over this lane's 16 keys
                float t0 = (p[0] + p[1]) + (p[2] + p[3]);
                float t1 = (p[4] + p[5]) + (p[6] + p[7]);
                float t2 = (p[8] + p[9]) + (p[10] + p[11]);
                float t3 = (p[12] + p[13]) + (p[14] + p[15]);
                rsum[qt] += (t0 + t1) + (t2 + t3);
                // pack key-pairs: u[i] = bf16(p[2i]) | bf16(p[2i+1])<<16
                unsigned u[8];
                #pragma unroll
                for (int i = 0; i < 8; ++i)
                    u[i] = __builtin_amdgcn_perm(__float_as_uint(p[2 * i + 1]),
                                                 __float_as_uint(p[2 * i]), 0x07060302u);
                // cross-half redistribute: swap(u0,u2)->slots{0,2}, swap(u1,u3)->slots{1,3}
                #pragma unroll
                for (int f = 0; f < 2; ++f) {
                    u32x2 e0 = __builtin_amdgcn_permlane32_swap(u[4 * f + 0], u[4 * f + 2], false, false);
                    u32x2 e1 = __builtin_amdgcn_permlane32_swap(u[4 * f + 1], u[4 * f + 3], false, false);
                    pf[qt][f] = mk8(e0.x, e1.x, e0.y, e1.y);
                }
            }
            // ---- PV half-tile: O += P @ V over keys kt2*32..+31 ----
            __builtin_amdgcn_s_setprio(1);
            #pragma unroll
            for (int dt = 0; dt < 2; ++dt)
                #pragma unroll
                for (int f = 0; f < 2; ++f) {
                    bf16x8 vf = *(const bf16x8*)&VtB[bufo + (dt * 32 + c32) * 64
                                    + ((((kt2 * 4 + f * 2 + hi) ^ (c32 & 7)) << 3))];
                    #pragma unroll
                    for (int qt = 0; qt < 2; ++qt)
                        oacc[qt][dt] = __builtin_amdgcn_mfma_f32_32x32x16_bf16(pf[qt][f], vf, oacc[qt][dt], 0, 0, 0);
                }
            __builtin_amdgcn_s_setprio(0);
        }
    }

    // ---- epilogue: combine hi-halves of rowsums, then the block's g-halves;
    //      write UNNORMALIZED bf16 O-partial + fp32 rowsum for this key-half ----
    #pragma unroll
    for (int qt = 0; qt < 2; ++qt) {
        u32x2 e = __builtin_amdgcn_permlane32_swap(__float_as_uint(rsum[qt]),
                                                   __float_as_uint(rsum[qt]), false, false);
        float tot = __uint_as_float(e.x) + __uint_as_float(e.y);
        Rs[w][qt][c32] = tot;   // both hi-lanes write identical value (benign)
    }
    __syncthreads();   // all loop reads done; Tiles dead -> overlay
    float (*Ep)[64][64] = (float (*)[64][64])&Tiles[0][0][0][0][0];   // 64 KB fp32 partials
    if (g == 1) {
        #pragma unroll
        for (int qt = 0; qt < 2; ++qt)
            #pragma unroll
            for (int dt = 0; dt < 2; ++dt) {
                const int d = dt * 32 + c32;
                #pragma unroll
                for (int rr = 0; rr < 4; ++rr) {
                    const int gq = (qt * 8 + 2 * rr + hi) ^ (d & 15);   // 16B-granule swizzle
                    f32x4 val = {oacc[qt][dt][rr * 4 + 0], oacc[qt][dt][rr * 4 + 1],
                                 oacc[qt][dt][rr * 4 + 2], oacc[qt][dt][rr * 4 + 3]};
                    *(f32x4*)&Ep[w - 4][d][gq * 4] = val;
                }
            }
    }
    __syncthreads();
    if (g == 0) {
        unsigned short* Op = kh ? Op1 : Op0;
        #pragma unroll
        for (int qt = 0; qt < 2; ++qt)
            #pragma unroll
            for (int dt = 0; dt < 2; ++dt) {
                const int d = dt * 32 + c32;
                #pragma unroll
                for (int rr = 0; rr < 4; ++rr) {
                    const int gq = (qt * 8 + 2 * rr + hi) ^ (d & 15);
                    f32x4 val = *(const f32x4*)&Ep[w][d][gq * 4];
                    oacc[qt][dt][rr * 4 + 0] += val[0];
                    oacc[qt][dt][rr * 4 + 1] += val[1];
                    oacc[qt][dt][rr * 4 + 2] += val[2];
                    oacc[qt][dt][rr * 4 + 3] += val[3];
                }
            }
        #pragma unroll
        for (int qt = 0; qt < 2; ++qt)
            #pragma unroll
            for (int rr = 0; rr < 4; ++rr) {
                f32x4 ra = *(const f32x4*)&Rs[w][qt][8 * rr + 4 * hi];
                f32x4 rb = *(const f32x4*)&Rs[w + 4][qt][8 * rr + 4 * hi];
                #pragma unroll
                for (int i = 0; i < 4; ++i) {
                    int row = q0 + qt * 32 + 8 * rr + 4 * hi + i;
                    if (c32 == 0)
                        Rp[(size_t)kh * L * H + (size_t)row * H + h] = ra[i] + rb[i];
                    #pragma unroll
                    for (int dt = 0; dt < 2; ++dt)
                        Op[(size_t)row * (H * DH) + h * DH + dt * 32 + c32] =
                            f2bf(oacc[qt][dt][rr * 4 + i]);
                }
            }
    }
}

// ---------------------------------------------------------------------------
// attn_combine: ob = (Op0 + Op1) / (Rp0 + Rp1). 4096x1024 bf16, grid 2048.
// ---------------------------------------------------------------------------
__global__ __launch_bounds__(256) void attn_combine(
        const unsigned short* __restrict__ Op0,
        const unsigned short* __restrict__ Op1,
        const float* __restrict__ Rp,
        unsigned short* __restrict__ ob) {
    const int idx  = blockIdx.x * 256 + threadIdx.x;
    const int base = idx * 8;                 // 8 d-elems within one (l, h)
    const int l = base >> 10;
    const int h = (base >> 6) & 15;
    const float inv = 1.0f / (Rp[(size_t)l * H + h] + Rp[(size_t)L * H + (size_t)l * H + h]);
    bf16x8 a = *(const bf16x8*)&Op0[base];
    bf16x8 b = *(const bf16x8*)&Op1[base];
    ushort4 o0, o1;
    unsigned short* o = (unsigned short*)&o0;
    #pragma unroll
    for (int i = 0; i < 4; ++i)
        o[i] = f2bf((bf2f((unsigned short)a[i]) + bf2f((unsigned short)b[i])) * inv);
    unsigned short* p = (unsigned short*)&o1;
    #pragma unroll
    for (int i = 0; i < 4; ++i)
        p[i] = f2bf((bf2f((unsigned short)a[4 + i]) + bf2f((unsigned short)b[4 + i])) * inv);
    *(ushort4*)&ob[base]     = o0;
    *(ushort4*)&ob[base + 4] = o1;
}

// ---------------------------------------------------------------------------
extern "C" void kernel_launch(void* const* d_in, const int* in_sizes, int n_in,
                              void* d_out, int out_size, void* d_ws, size_t ws_size,
                              hipStream_t stream) {
    const float* x  = (const float*)d_in[0];
    const float* Wq = (const float*)d_in[1];
    const float* Wk = (const float*)d_in[2];
    const float* Wv = (const float*)d_in[3];
    const float* Wo = (const float*)d_in[4];
    float* out = (float*)d_out;

    // ---- workspace (~26.2 MB) + overlays ----
    char* ws = (char*)d_ws;
    unsigned short* xb    = (unsigned short*)ws;                      // 8.39 MB; Op0 overlays (xb dead after QKV)
    unsigned short* qb    = (unsigned short*)(ws + 8388608);          // 8.39 MB; ob overlays (qb dead after attn)
    unsigned short* kb    = (unsigned short*)(ws + 16777216);         // 2.10 MB (K per-head [kv][l][DH])
    unsigned short* vbT   = (unsigned short*)(ws + 18874368);         // 2.10 MB (V^T [kv*DH+d][l])
    unsigned short* WqkvT = (unsigned short*)(ws + 20971520);         // 3.15 MB; Rp overlays (dead after QKV)
    unsigned short* WoT   = (unsigned short*)(ws + 24117248);         // 2.10 MB (live until step 5)

    unsigned short* Op0 = xb;                       // bf16 partial, key-half 0
    unsigned short* Op1 = (unsigned short*)d_out;   // bf16 partial, key-half 1 (d_out dead until step 5)
    float*          Rp  = (float*)WqkvT;            // 512 KB fp32 rowsums [2][L][H]
    unsigned short* ob  = qb;                       // combined bf16 attention output

    dim3 blk(256);

    // 1) convert + transpose everything
    prep_kernel<<<6656, blk, 0, stream>>>(x, Wq, Wk, Wv, Wo, xb, WqkvT, WoT);

    // 2) fused QKV projection + RoPE + bf16 pack (K per-head, V transposed)
    gemm_qkv_rope<<<dim3(12, 64), blk, 0, stream>>>(xb, WqkvT, qb, kb, vbT);

    // 3) attention: 512 blocks (key-half grid split) -> 2 blocks/CU, 4 waves/SIMD
    attn_mfma_kernel<<<dim3(L / 64, KV, 2), dim3(512), 0, stream>>>(qb, kb, vbT, Op0, Op1, Rp);

    // 4) combine key-halves + normalize
    attn_combine<<<2048, blk, 0, stream>>>(Op0, Op1, Rp, ob);

    // 5) output projection (64x128 tiles, 512 blocks)
    gemm_bf16<<<dim3(D / 128, L / 64), blk, 0, stream>>>(ob, WoT, out, L, D, D);
}